// Round 18
// baseline (109.747 us; speedup 1.0000x reference)
//
#include <hip/hip_runtime.h>
#include <math.h>

#define TILE 128

typedef __attribute__((ext_vector_type(4))) float f32x4;
typedef __attribute__((ext_vector_type(2))) long long llong2;

// constants: 1/T, 1/(T*ln2); fp8 path uses x8-scaled inputs -> /64 variants
#define INV_T    14.285714285714286f
#define K2C      20.60992915f
#define K2C8     0.32203014296875f    // K2C / 64
#define INV_T64  0.22321428571428573f // INV_T / 64
#define TIME_THR 5000000

__device__ __forceinline__ unsigned pack_bf16x2(float lo, float hi) {
  unsigned a = __float_as_uint(lo);
  unsigned b = __float_as_uint(hi);
  a = (a + 0x7FFFu + ((a >> 16) & 1u)) >> 16;
  b = (b + 0x7FFFu + ((b >> 16) & 1u)) & 0xFFFF0000u;
  return b | a;
}

// float -> OCP e4m3fn, round-to-nearest-even, clamp to 448.
__device__ __forceinline__ unsigned f32_to_e4m3(float x) {
  unsigned u = __float_as_uint(x);
  unsigned s = (u >> 24) & 0x80u;
  int e = (int)((u >> 23) & 0xffu) - 127;
  unsigned m = u & 0x7fffffu;
  if (e < -9) return s;  // underflow to zero
  if (e < -6) {          // subnormal (quantum 2^-9)
    int sh = 20 + (-6 - e);
    unsigned full = (1u << 23) | m;
    unsigned q = full >> sh;
    unsigned rem = full & ((1u << sh) - 1u);
    unsigned half = 1u << (sh - 1);
    if (rem > half || (rem == half && (q & 1u))) q++;
    return s | q;  // q==8 carries naturally into exp=1
  }
  unsigned q = m >> 20;
  unsigned rem = m & 0xfffffu;
  if (rem > 0x80000u || (rem == 0x80000u && (q & 1u))) q++;
  int ee = e;
  if (q == 8u) { q = 0u; ee++; }
  if (ee > 8 || (ee == 8 && q == 7u)) return s | 0x7eu;  // clamp 448
  return s | (unsigned)((ee + 7) << 3) | q;
}

__device__ __forceinline__ void gl_lds16(const void* g, void* l) {
  __builtin_amdgcn_global_load_lds(
      (const __attribute__((address_space(1))) unsigned int*)g,
      (__attribute__((address_space(3))) unsigned int*)l, 16, 0, 0);
}

// MODE=2: fp8 e4m3 (x8-scaled), K-tile=128, 128B LDS rows (R17: 0 bank
//   conflicts). R18: 3 blocks/CU — LDS diet to 50KB via SINGLE-buffered B
//   panel (A stays double-buffered). Choreography (FIFO-exact):
//   prologue A0,B0; step: stageA(ts+1) -> vmcnt(4) [drains A(ts),B(ts)]
//   -> barrier -> 16 ds_read -> lgkm(0) -> 64 MFMA -> barrier ->
//   stageB(ts+1) into the single B buffer (all readers of B(ts) passed
//   barrier2; B(ts+1) readers gate on next vmcnt+barrier).
//   Registers: fp8 frags (64) + acc (64) fit the 3-waves/EU 170 budget —
//   unlike R10/R11's 4-waves/EU 128-budget spills.
// MODE=0: fp32 src, register staging + conversion + atomicAdd (fallback).
template <int MODE>
__device__ __forceinline__ void infonce_body(
    const float* __restrict__ desc, const unsigned char* __restrict__ desc8,
    const int* __restrict__ seq, const int* __restrict__ tmid,
    float* __restrict__ p_se, float* __restrict__ p_ps,
    float* __restrict__ p_pc, int B, int D, int NB) {
  // ---- triangular (upper) block decode, with XCD-aware swizzle ----
  const int T = NB * (NB + 1) / 2;
  int t = blockIdx.x;
  if ((T & 7) == 0) t = (t & 7) * (T >> 3) + (t >> 3);
  float fn = (float)NB + 0.5f;
  int r = (int)(fn - sqrtf(fmaxf(fn * fn - 2.0f * (float)t, 0.0f)));
  if (r < 0) r = 0;
  if (r > NB - 1) r = NB - 1;
  auto Sf = [NB](int rr) { return rr * NB - ((rr * (rr - 1)) >> 1); };
  while (r > 0 && Sf(r) > t) --r;
  while (r < NB - 1 && Sf(r + 1) <= t) ++r;
  const int rb = r;
  const int cb = rb + (t - Sf(rb));
  const bool upper = (cb != rb);

  const int row0 = rb * TILE;
  const int col0 = cb * TILE;

  const int tid = threadIdx.x;
  const int l = tid & 63;
  const int w = tid >> 6;          // wave id 0..3 (2x2)
  const int wrow = (w >> 1) << 6;  // 0 or 64
  const int wcol = (w & 1) << 6;   // 0 or 64
  const int lr = l & 15;
  const int kg = l >> 4;

  f32x4 acc[4][4];
#pragma unroll
  for (int m = 0; m < 4; ++m)
#pragma unroll
    for (int n = 0; n < 4; ++n) acc[m][n] = (f32x4){0.f, 0.f, 0.f, 0.f};

  // MODE=0 staging geometry
  const int sr = tid >> 3;
  const int sc = tid & 7;

  if (MODE == 2) {
    __shared__ __align__(16) unsigned char lA8[2][TILE][128];
    __shared__ __align__(16) unsigned char lB8[TILE][128];
    __shared__ int mseq_r[TILE], mtim_r[TILE], mseq_c[TILE], mtim_c[TILE];

    // stage row/col metadata (drained by compiler before prologue walls)
    if (tid < TILE) {
      mseq_r[tid] = seq[row0 + tid];
      mtim_r[tid] = tmid[row0 + tid];
      mseq_c[tid] = seq[col0 + tid];
      mtim_c[tid] = tmid[col0 + tid];
    }

    const int NT = D >> 7;  // K-tile = 128
    // staging: panel = 128 rows x 128 B = 1024 granules of 16B; thread tid
    // stages granules q*256+tid (q=0..3): row = q*32 + (tid>>3), chunk
    // p = tid&7. Data pre-permuted in global (conv_fp8) -> pure linear
    // copy (rule #21).
    const unsigned char* pa =
        desc8 + (size_t)(row0 + (tid >> 3)) * D + (tid & 7) * 16;
    const unsigned char* pb =
        desc8 + (size_t)(col0 + (tid >> 3)) * D + (tid & 7) * 16;
    const size_t rstep = (size_t)32 * D;  // +32 rows per q

    auto stageA = [&](int bu_, int tt) {
      const int off = tt << 7;
#pragma unroll
      for (int q = 0; q < 4; ++q)
        gl_lds16(pa + (size_t)q * rstep + off,
                 (char*)&lA8[bu_][0][0] + (q << 12) + tid * 16);
    };
    auto stageB = [&](int tt) {
      const int off = tt << 7;
#pragma unroll
      for (int q = 0; q < 4; ++q)
        gl_lds16(pb + (size_t)q * rstep + off,
                 (char*)&lB8[0][0] + (q << 12) + tid * 16);
    };

    __builtin_amdgcn_sched_barrier(0);
    stageA(0, 0);  // 4 events
    stageB(0);     // 4 events
    __builtin_amdgcn_sched_barrier(0);

    for (int ts = 0; ts < NT; ++ts) {
      const int bu = ts & 1;
      // issue next A-panel; vmcnt(4) drains A(ts)+B(ts), keeps A(ts+1)
      if (ts + 1 < NT) {
        stageA(bu ^ 1, ts + 1);
        __builtin_amdgcn_sched_barrier(0);
        asm volatile("s_waitcnt vmcnt(4)" ::: "memory");
      } else {
        asm volatile("s_waitcnt vmcnt(0)" ::: "memory");
      }
      __builtin_amdgcn_sched_barrier(0);
      __builtin_amdgcn_s_barrier();  // A[bu] + B globally ready
      __builtin_amdgcn_sched_barrier(0);

      // 16 ds_read_b128, zero-conflict geometry (128B rows, row&7 XOR);
      // each read: lo 8B = MFMA step 2*j2, hi = 2*j2+1.
      llong2 av[4][2], bv[4][2];
#pragma unroll
      for (int m = 0; m < 4; ++m) {
        const int row = wrow + (m << 4) + lr;
#pragma unroll
        for (int j2 = 0; j2 < 2; ++j2) {
          const int ch = ((j2 << 2) + kg) ^ (row & 7);
          av[m][j2] =
              *reinterpret_cast<const llong2*>(&lA8[bu][row][ch << 4]);
        }
      }
#pragma unroll
      for (int n = 0; n < 4; ++n) {
        const int row = wcol + (n << 4) + lr;
#pragma unroll
        for (int j2 = 0; j2 < 2; ++j2) {
          const int ch = ((j2 << 2) + kg) ^ (row & 7);
          bv[n][j2] = *reinterpret_cast<const llong2*>(&lB8[row][ch << 4]);
        }
      }
      __builtin_amdgcn_sched_barrier(0);
      asm volatile("s_waitcnt lgkmcnt(0)" ::: "memory");
      __builtin_amdgcn_sched_barrier(0);  // rule #18: pin MFMA below wait
      __builtin_amdgcn_s_setprio(1);
#pragma unroll
      for (int j2 = 0; j2 < 2; ++j2)
#pragma unroll
        for (int kk = 0; kk < 2; ++kk)
#pragma unroll
          for (int m = 0; m < 4; ++m)
#pragma unroll
            for (int n = 0; n < 4; ++n)
              acc[m][n] = __builtin_amdgcn_mfma_f32_16x16x32_fp8_fp8(
                  av[m][j2][kk], bv[n][j2][kk], acc[m][n], 0, 0, 0);
      __builtin_amdgcn_s_setprio(0);
      __builtin_amdgcn_sched_barrier(0);
      __builtin_amdgcn_s_barrier();  // all waves done reading A[bu], B
      __builtin_amdgcn_sched_barrier(0);
      if (ts + 1 < NT) stageB(ts + 1);  // refill single B buffer
      __builtin_amdgcn_sched_barrier(0);
    }
    __syncthreads();  // full drain before LDS reuse

    // ---- epilogue: atomic-free partials (LDS reuse) ----
    float* rowred = (float*)&lA8[0][0][0];  // [2][TILE][3]
    float* colred = (float*)&lB8[0][0];     // [2][TILE][3]

    int cseq[4], ctim[4], gcol[4];
#pragma unroll
    for (int n = 0; n < 4; ++n) {
      const int cl = wcol + (n << 4) + lr;
      cseq[n] = mseq_c[cl];
      ctim[n] = mtim_c[cl];
      gcol[n] = col0 + cl;
    }
    float colse[4] = {0.f, 0.f, 0.f, 0.f};
    float colpd[4] = {0.f, 0.f, 0.f, 0.f};
    float colpc[4] = {0.f, 0.f, 0.f, 0.f};

#pragma unroll
    for (int m = 0; m < 4; ++m) {
#pragma unroll
      for (int reg = 0; reg < 4; ++reg) {
        const int rl = wrow + (m << 4) + (kg << 2) + reg;
        const int growg = row0 + rl;
        const int rs = mseq_r[rl];
        const int rt = mtim_r[rl];
        float se = 0.f, pd = 0.f, pcnt = 0.f;
#pragma unroll
        for (int n = 0; n < 4; ++n) {
          const float dot = acc[m][n][reg];
          const float e = exp2f(fmaf(dot, K2C8, -K2C));
          const bool nd = (growg != gcol[n]);
          int dt = rt - ctim[n];
          dt = dt < 0 ? -dt : dt;
          const bool pos = nd && (rs == cseq[n]) && (dt < TIME_THR);
          const float ev = nd ? e : 0.f;
          const float dv = pos ? dot : 0.f;
          const float cv = pos ? 1.f : 0.f;
          se += ev;
          pd += dv;
          pcnt += cv;
          colse[n] += ev;
          colpd[n] += dv;
          colpc[n] += cv;
        }
#pragma unroll
        for (int s = 1; s < 16; s <<= 1) {
          se += __shfl_xor(se, s);
          pd += __shfl_xor(pd, s);
          pcnt += __shfl_xor(pcnt, s);
        }
        if (lr == 0) {
          const int half = wcol >> 6;
          float* rr3 = rowred + ((size_t)(half * TILE + rl)) * 3;
          rr3[0] = se;
          rr3[1] = pd;
          rr3[2] = pcnt;
        }
      }
    }
    if (upper) {
#pragma unroll
      for (int n = 0; n < 4; ++n) {
        float cs = colse[n], cp = colpd[n], cc = colpc[n];
        cs += __shfl_xor(cs, 16);
        cp += __shfl_xor(cp, 16);
        cc += __shfl_xor(cc, 16);
        cs += __shfl_xor(cs, 32);
        cp += __shfl_xor(cp, 32);
        cc += __shfl_xor(cc, 32);
        if (l < 16) {
          const int half = wrow >> 6;
          const int cl = wcol + (n << 4) + lr;
          float* cr3 = colred + ((size_t)(half * TILE + cl)) * 3;
          cr3[0] = cs;
          cr3[1] = cp;
          cr3[2] = cc;
        }
      }
    }
    __syncthreads();

    if (tid < TILE) {
      const int row = tid;
      const float se =
          rowred[(size_t)row * 3 + 0] + rowred[(size_t)(TILE + row) * 3 + 0];
      const float pd =
          rowred[(size_t)row * 3 + 1] + rowred[(size_t)(TILE + row) * 3 + 1];
      const float pc =
          rowred[(size_t)row * 3 + 2] + rowred[(size_t)(TILE + row) * 3 + 2];
      const size_t o = (size_t)cb * B + row0 + row;
      p_se[o] = se;
      p_ps[o] = pd * INV_T64;
      p_pc[o] = pc;
    } else if (upper && tid < 2 * TILE) {
      const int col = tid - TILE;
      const float se =
          colred[(size_t)col * 3 + 0] + colred[(size_t)(TILE + col) * 3 + 0];
      const float pd =
          colred[(size_t)col * 3 + 1] + colred[(size_t)(TILE + col) * 3 + 1];
      const float pc =
          colred[(size_t)col * 3 + 2] + colred[(size_t)(TILE + col) * 3 + 2];
      const size_t o = (size_t)rb * B + col0 + col;
      p_se[o] = se;
      p_ps[o] = pd * INV_T64;
      p_pc[o] = pc;
    }
  } else {
    // MODE 0 fallback: fp32 -> bf16 in-loop, simple 2-barrier loop,
    // atomicAdd epilogue.
    __shared__ __align__(16) unsigned short lAw[TILE][64];
    __shared__ __align__(16) unsigned short lBw[TILE][64];
    __shared__ int mseq_r[TILE], mtim_r[TILE], mseq_c[TILE], mtim_c[TILE];
    typedef __attribute__((ext_vector_type(8))) short short8v;

    if (tid < TILE) {
      mseq_r[tid] = seq[row0 + tid];
      mtim_r[tid] = tmid[row0 + tid];
      mseq_c[tid] = seq[col0 + tid];
      mtim_c[tid] = tmid[col0 + tid];
    }
    for (int k0 = 0; k0 < D; k0 += 64) {
      __syncthreads();
#pragma unroll
      for (int p = 0; p < 4; ++p) {
        const int rr = (p << 5) + sr;
        const float* gA = desc + (size_t)(row0 + rr) * D + k0 + (sc << 3);
        const float4 fa0 = *reinterpret_cast<const float4*>(gA);
        const float4 fa1 = *reinterpret_cast<const float4*>(gA + 4);
        const float* gB = desc + (size_t)(col0 + rr) * D + k0 + (sc << 3);
        const float4 fb0 = *reinterpret_cast<const float4*>(gB);
        const float4 fb1 = *reinterpret_cast<const float4*>(gB + 4);
        uint4 wa, wb;
        wa.x = pack_bf16x2(fa0.x, fa0.y);
        wa.y = pack_bf16x2(fa0.z, fa0.w);
        wa.z = pack_bf16x2(fa1.x, fa1.y);
        wa.w = pack_bf16x2(fa1.z, fa1.w);
        wb.x = pack_bf16x2(fb0.x, fb0.y);
        wb.y = pack_bf16x2(fb0.z, fb0.w);
        wb.z = pack_bf16x2(fb1.x, fb1.y);
        wb.w = pack_bf16x2(fb1.z, fb1.w);
        const int dst = (sc ^ (rr & 7)) << 3;
        *reinterpret_cast<uint4*>(&lAw[rr][dst]) = wa;
        *reinterpret_cast<uint4*>(&lBw[rr][dst]) = wb;
      }
      __syncthreads();
#pragma unroll
      for (int kk = 0; kk < 2; ++kk) {
        short8v af[4], bf[4];
#pragma unroll
        for (int m = 0; m < 4; ++m) {
          const int rowa = wrow + (m << 4) + lr;
          const int ch = ((kk << 2) + kg) ^ (rowa & 7);
          af[m] = *reinterpret_cast<const short8v*>(&lAw[rowa][ch << 3]);
        }
#pragma unroll
        for (int n = 0; n < 4; ++n) {
          const int rowb = wcol + (n << 4) + lr;
          const int ch = ((kk << 2) + kg) ^ (rowb & 7);
          bf[n] = *reinterpret_cast<const short8v*>(&lBw[rowb][ch << 3]);
        }
#pragma unroll
        for (int m = 0; m < 4; ++m)
#pragma unroll
          for (int n = 0; n < 4; ++n)
            acc[m][n] = __builtin_amdgcn_mfma_f32_16x16x32_bf16(af[m], bf[n],
                                                                acc[m][n], 0, 0, 0);
      }
    }
    __syncthreads();

    int cseq[4], ctim[4], gcol[4];
#pragma unroll
    for (int n = 0; n < 4; ++n) {
      const int cl = wcol + (n << 4) + lr;
      cseq[n] = mseq_c[cl];
      ctim[n] = mtim_c[cl];
      gcol[n] = col0 + cl;
    }
    float colse[4] = {0.f, 0.f, 0.f, 0.f};
    float colpd[4] = {0.f, 0.f, 0.f, 0.f};
    float colpc[4] = {0.f, 0.f, 0.f, 0.f};

#pragma unroll
    for (int m = 0; m < 4; ++m) {
#pragma unroll
      for (int reg = 0; reg < 4; ++reg) {
        const int rl = wrow + (m << 4) + (kg << 2) + reg;
        const int growg = row0 + rl;
        const int rs = mseq_r[rl];
        const int rt = mtim_r[rl];
        float se = 0.f, pd = 0.f, pcnt = 0.f;
#pragma unroll
        for (int n = 0; n < 4; ++n) {
          const float dot = acc[m][n][reg];
          const float e = exp2f(fmaf(dot, K2C, -K2C));
          const bool nd = (growg != gcol[n]);
          int dt = rt - ctim[n];
          dt = dt < 0 ? -dt : dt;
          const bool pos = nd && (rs == cseq[n]) && (dt < TIME_THR);
          const float ev = nd ? e : 0.f;
          const float dv = pos ? dot : 0.f;
          const float cv = pos ? 1.f : 0.f;
          se += ev;
          pd += dv;
          pcnt += cv;
          if (upper) {
            colse[n] += ev;
            colpd[n] += dv;
            colpc[n] += cv;
          }
        }
#pragma unroll
        for (int s = 1; s < 16; s <<= 1) {
          se += __shfl_xor(se, s);
          pd += __shfl_xor(pd, s);
          pcnt += __shfl_xor(pcnt, s);
        }
        if ((l & 15) == 0) {
          atomicAdd(&p_se[growg], se);
          atomicAdd(&p_ps[growg], pd * INV_T);
          atomicAdd(&p_pc[growg], pcnt);
        }
      }
    }
    if (upper) {
#pragma unroll
      for (int n = 0; n < 4; ++n) {
        float cs = colse[n], cp = colpd[n], cc = colpc[n];
        cs += __shfl_xor(cs, 16);
        cp += __shfl_xor(cp, 16);
        cc += __shfl_xor(cc, 16);
        cs += __shfl_xor(cs, 32);
        cp += __shfl_xor(cp, 32);
        cc += __shfl_xor(cc, 32);
        if (kg == 0) {
          atomicAdd(&p_se[gcol[n]], cs);
          atomicAdd(&p_ps[gcol[n]], cp * INV_T);
          atomicAdd(&p_pc[gcol[n]], cc);
        }
      }
    }
  }
}

__global__ __launch_bounds__(256, 3) void infonce_main2(
    const float* desc, const unsigned char* desc8, const int* seq,
    const int* tmid, float* p_se, float* p_ps, float* p_pc, int B, int D,
    int NB) {
  infonce_body<2>(desc, desc8, seq, tmid, p_se, p_ps, p_pc, B, D, NB);
}
__global__ __launch_bounds__(256, 2) void infonce_main0(
    const float* desc, const unsigned char* desc8, const int* seq,
    const int* tmid, float* p_se, float* p_ps, float* p_pc, int B, int D,
    int NB) {
  infonce_body<0>(desc, desc8, seq, tmid, p_se, p_ps, p_pc, B, D, NB);
}

// fp32 -> fp8 e4m3 (x8 scale), K-tile-128 interleave + row&7 XOR:
// out chunk u (16B): row r = u/(D/16), in-row chunk cc; kt = cc>>3,
// p = cc&7, g = p ^ (r&7), j2 = g>>2, kgc = g&3;
// lo 8B: k = kt*128 + j2*64 + kgc*8 ..; hi 8B: +32.
__global__ __launch_bounds__(256) void conv_fp8(const float* __restrict__ in,
                                                unsigned char* __restrict__ out,
                                                int D, int nchunk) {
  const int u = blockIdx.x * 256 + threadIdx.x;
  if (u >= nchunk) return;
  const int cpr = D >> 4;  // chunks per row
  const int r = u / cpr;
  const int cc = u - r * cpr;
  const int kt = cc >> 3;
  const int p = cc & 7;
  const int g = p ^ (r & 7);
  const int j2 = g >> 2;
  const int kgc = g & 3;
  const float* src = in + (size_t)r * D + (kt << 7) + (j2 << 6) + (kgc << 3);
  const float4 f0 = *reinterpret_cast<const float4*>(src);
  const float4 f1 = *reinterpret_cast<const float4*>(src + 4);
  const float4 g0 = *reinterpret_cast<const float4*>(src + 32);
  const float4 g1 = *reinterpret_cast<const float4*>(src + 36);
  unsigned char b[16];
  b[0] = f32_to_e4m3(f0.x * 8.f);
  b[1] = f32_to_e4m3(f0.y * 8.f);
  b[2] = f32_to_e4m3(f0.z * 8.f);
  b[3] = f32_to_e4m3(f0.w * 8.f);
  b[4] = f32_to_e4m3(f1.x * 8.f);
  b[5] = f32_to_e4m3(f1.y * 8.f);
  b[6] = f32_to_e4m3(f1.z * 8.f);
  b[7] = f32_to_e4m3(f1.w * 8.f);
  b[8] = f32_to_e4m3(g0.x * 8.f);
  b[9] = f32_to_e4m3(g0.y * 8.f);
  b[10] = f32_to_e4m3(g0.z * 8.f);
  b[11] = f32_to_e4m3(g0.w * 8.f);
  b[12] = f32_to_e4m3(g1.x * 8.f);
  b[13] = f32_to_e4m3(g1.y * 8.f);
  b[14] = f32_to_e4m3(g1.z * 8.f);
  b[15] = f32_to_e4m3(g1.w * 8.f);
  uint4 wv;
  unsigned* wp = (unsigned*)&wv;
#pragma unroll
  for (int d = 0; d < 4; ++d)
    wp[d] = (unsigned)b[d * 4] | ((unsigned)b[d * 4 + 1] << 8) |
            ((unsigned)b[d * 4 + 2] << 16) | ((unsigned)b[d * 4 + 3] << 24);
  *reinterpret_cast<uint4*>(out + (size_t)u * 16) = wv;
}

// 4 threads per row (NB quarters), 64 rows/block -> B/64 blocks.
__global__ __launch_bounds__(256) void reduce_parts4(
    const float* __restrict__ p_se, const float* __restrict__ p_ps,
    const float* __restrict__ p_pc, float* __restrict__ bnum,
    float* __restrict__ bcnt, int B, int NB) {
  const int tid = threadIdx.x;
  const int rloc = tid & 63;
  const int chunk = tid >> 6;  // 0..3
  const int row = blockIdx.x * 64 + rloc;
  const int jpc = NB >> 2;
  float se = 0.f, ps = 0.f, pc = 0.f;
  for (int j = chunk * jpc; j < (chunk + 1) * jpc; ++j) {
    const size_t o = (size_t)j * B + row;
    se += p_se[o];
    ps += p_ps[o];
    pc += p_pc[o];
  }
  __shared__ float s3[3][4][64];
  s3[0][chunk][rloc] = se;
  s3[1][chunk][rloc] = ps;
  s3[2][chunk][rloc] = pc;
  __syncthreads();
  if (tid < 64) {
    const float tse = s3[0][0][tid] + s3[0][1][tid] + s3[0][2][tid] + s3[0][3][tid];
    const float tps = s3[1][0][tid] + s3[1][1][tid] + s3[1][2][tid] + s3[1][3][tid];
    const float tpc = s3[2][0][tid] + s3[2][1][tid] + s3[2][2][tid] + s3[2][3][tid];
    float a = tpc * (logf(tse) + INV_T) - tps;
    float b = tpc;
#pragma unroll
    for (int s = 1; s < 64; s <<= 1) {
      a += __shfl_xor(a, s);
      b += __shfl_xor(b, s);
    }
    if (tid == 0) {
      bnum[blockIdx.x] = a;
      bcnt[blockIdx.x] = b;
    }
  }
}

__global__ __launch_bounds__(256) void final_reduce(
    const float* __restrict__ bnum, const float* __restrict__ bcnt,
    float* __restrict__ out, int n) {
  __shared__ float sn[256];
  __shared__ float sc[256];
  const int tid = threadIdx.x;
  float a = 0.f, b = 0.f;
  for (int i = tid; i < n; i += 256) {
    a += bnum[i];
    b += bcnt[i];
  }
  sn[tid] = a;
  sc[tid] = b;
  __syncthreads();
  for (int s = 128; s > 0; s >>= 1) {
    if (tid < s) {
      sn[tid] += sn[tid + s];
      sc[tid] += sc[tid + s];
    }
    __syncthreads();
  }
  if (tid == 0) out[0] = sn[0] / fmaxf(sc[0], 1.f);
}

// fallback finalize for atomic mode (reads flat a_se/a_ps/a_pc)
__global__ __launch_bounds__(1024) void infonce_finalize(
    const float* __restrict__ a_se, const float* __restrict__ a_ps,
    const float* __restrict__ a_pc, float* __restrict__ out, int B) {
  __shared__ float sn[1024];
  __shared__ float sc[1024];
  const int tid = threadIdx.x;
  float num = 0.f, cnt = 0.f;
  for (int i = tid; i < B; i += 1024) {
    const float c = a_pc[i];
    num += c * (logf(a_se[i]) + INV_T) - a_ps[i];
    cnt += c;
  }
  sn[tid] = num;
  sc[tid] = cnt;
  __syncthreads();
  for (int s = 512; s > 0; s >>= 1) {
    if (tid < s) {
      sn[tid] += sn[tid + s];
      sc[tid] += sc[tid + s];
    }
    __syncthreads();
  }
  if (tid == 0) out[0] = sn[0] / fmaxf(sc[0], 1.f);
}

extern "C" void kernel_launch(void* const* d_in, const int* in_sizes, int n_in,
                              void* d_out, int out_size, void* d_ws, size_t ws_size,
                              hipStream_t stream) {
  (void)n_in;
  (void)out_size;
  const float* desc = (const float*)d_in[0];
  const int* seq = (const int*)d_in[1];
  const int* tmid = (const int*)d_in[2];
  const int B = in_sizes[1];
  const int D = in_sizes[0] / B;
  const int NB = B / TILE;
  const int T = NB * (NB + 1) / 2;

  const size_t desc8_bytes = (size_t)B * D;
  const size_t parts_elems = (size_t)B * NB;
  const size_t nb1 = (size_t)B / 64;  // reduce_parts4 blocks (max case)
  const size_t need8 = desc8_bytes + 3 * parts_elems * 4 + 2 * nb1 * 4;

  if ((B & 255) == 0 && (D & 127) == 0 && ws_size >= need8) {
    unsigned char* desc8 = (unsigned char*)d_ws;
    float* p_se = (float*)((char*)d_ws + desc8_bytes);
    float* p_ps = p_se + parts_elems;
    float* p_pc = p_ps + parts_elems;
    float* bnum = p_pc + parts_elems;
    float* bcnt = bnum + nb1;
    const int nchunk = (int)(((size_t)B * D) >> 4);
    conv_fp8<<<(nchunk + 255) / 256, 256, 0, stream>>>(desc, desc8, D, nchunk);
    infonce_main2<<<T, 256, 0, stream>>>(desc, desc8, seq, tmid, p_se, p_ps,
                                         p_pc, B, D, NB);
    const int nrb = B / 64;
    reduce_parts4<<<nrb, 256, 0, stream>>>(p_se, p_ps, p_pc, bnum, bcnt, B, NB);
    final_reduce<<<1, 256, 0, stream>>>(bnum, bcnt, (float*)d_out, nrb);
  } else {
    float* a_se = (float*)d_ws;
    float* a_ps = a_se + B;
    float* a_pc = a_ps + B;
    hipMemsetAsync(d_ws, 0, (size_t)3 * B * sizeof(float), stream);
    infonce_main0<<<T, 256, 0, stream>>>(desc, nullptr, seq, tmid, a_se, a_ps,
                                         a_pc, B, D, NB);
    infonce_finalize<<<1, 1024, 0, stream>>>(a_se, a_ps, a_pc, (float*)d_out, B);
  }
}

// Round 19
// 92.686 us; speedup vs baseline: 1.1841x; 1.1841x over previous
//
#include <hip/hip_runtime.h>
#include <math.h>

#define TILE 128

typedef __attribute__((ext_vector_type(4))) float f32x4;
typedef __attribute__((ext_vector_type(2))) long long llong2;

// constants: 1/T, 1/(T*ln2); fp8 path uses x8-scaled inputs -> /64 variants
#define INV_T    14.285714285714286f
#define K2C      20.60992915f
#define K2C8     0.32203014296875f    // K2C / 64
#define INV_T64  0.22321428571428573f // INV_T / 64
#define TIME_THR 5000000

__device__ __forceinline__ unsigned pack_bf16x2(float lo, float hi) {
  unsigned a = __float_as_uint(lo);
  unsigned b = __float_as_uint(hi);
  a = (a + 0x7FFFu + ((a >> 16) & 1u)) >> 16;
  b = (b + 0x7FFFu + ((b >> 16) & 1u)) & 0xFFFF0000u;
  return b | a;
}

// float -> OCP e4m3fn, round-to-nearest-even, clamp to 448.
__device__ __forceinline__ unsigned f32_to_e4m3(float x) {
  unsigned u = __float_as_uint(x);
  unsigned s = (u >> 24) & 0x80u;
  int e = (int)((u >> 23) & 0xffu) - 127;
  unsigned m = u & 0x7fffffu;
  if (e < -9) return s;
  if (e < -6) {
    int sh = 20 + (-6 - e);
    unsigned full = (1u << 23) | m;
    unsigned q = full >> sh;
    unsigned rem = full & ((1u << sh) - 1u);
    unsigned half = 1u << (sh - 1);
    if (rem > half || (rem == half && (q & 1u))) q++;
    return s | q;
  }
  unsigned q = m >> 20;
  unsigned rem = m & 0xfffffu;
  if (rem > 0x80000u || (rem == 0x80000u && (q & 1u))) q++;
  int ee = e;
  if (q == 8u) { q = 0u; ee++; }
  if (ee > 8 || (ee == 8 && q == 7u)) return s | 0x7eu;
  return s | (unsigned)((ee + 7) << 3) | q;
}

__device__ __forceinline__ void gl_lds16(const void* g, void* l) {
  __builtin_amdgcn_global_load_lds(
      (const __attribute__((address_space(1))) unsigned int*)g,
      (__attribute__((address_space(3))) unsigned int*)l, 16, 0, 0);
}

// PERSISTENT fp8 kernel: grid = min(T,512) (exactly the 2-blocks/CU x 256CU
// residency). Each block loops over tiles j, j+G, ... ; during the LAST
// K-step of tile j it prefetches tile j+G's first panels into the same
// 8-event FIFO slot per-tile prefetch used -> vmcnt counting identical to
// R17's proven choreography; inter-tile staging hides under MFMA+epilogue.
// Epilogue: dedicated red-buffers (no aliasing with in-flight gl_lds) and
// raw lgkmcnt(0)+s_barrier (NOT __syncthreads: that emits vmcnt(0) and
// would drain the cross-tile prefetch). Meta read direct from global.
// Geometry/regs: R17's only-fitting point — (256,2), fp8 frags+acc, 128B
// LDS rows (0 bank conflicts), K-tile=128.
__global__ __launch_bounds__(256, 2) void infonce_pers(
    const unsigned char* __restrict__ desc8, const int* __restrict__ seq,
    const int* __restrict__ tmid, float* __restrict__ p_se,
    float* __restrict__ p_ps, float* __restrict__ p_pc, int B, int D, int NB,
    int G) {
  __shared__ __align__(16) unsigned char lA8[2][TILE][128];
  __shared__ __align__(16) unsigned char lB8[2][TILE][128];
  __shared__ float redR[2 * TILE * 3];
  __shared__ float redC[2 * TILE * 3];

  const int T = NB * (NB + 1) / 2;
  const int tid = threadIdx.x;
  const int l = tid & 63;
  const int w = tid >> 6;          // wave id 0..3 (2x2)
  const int wrow = (w >> 1) << 6;  // 0 or 64
  const int wcol = (w & 1) << 6;   // 0 or 64
  const int lr = l & 15;
  const int kg = l >> 4;
  const int NT = D >> 7;  // K-tile = 128

  // triangular decode with XCD swizzle (logical idx -> rb,cb)
  auto decode = [&](int idx, int& rb_, int& cb_) {
    int t = idx;
    if ((T & 7) == 0) t = (t & 7) * (T >> 3) + (t >> 3);
    float fn = (float)NB + 0.5f;
    int r = (int)(fn - sqrtf(fmaxf(fn * fn - 2.0f * (float)t, 0.0f)));
    if (r < 0) r = 0;
    if (r > NB - 1) r = NB - 1;
    auto Sf = [&](int rr) { return rr * NB - ((rr * (rr - 1)) >> 1); };
    while (r > 0 && Sf(r) > t) --r;
    while (r < NB - 1 && Sf(r + 1) <= t) ++r;
    rb_ = r;
    cb_ = r + (t - Sf(r));
  };

  // staging: panel = 128 rows x 128B; thread stages granules q*256+tid
  // (row q*32 + (tid>>3), chunk tid&7); data pre-permuted in global
  // (conv_fp8) -> pure linear copy (rule #21). 4 events per stage call.
  const size_t rstep = (size_t)32 * D;
  const size_t lane_off = (size_t)(tid >> 3) * D + (size_t)(tid & 7) * 16;
  auto stage = [&](const unsigned char* src, unsigned char* dst) {
#pragma unroll
    for (int q = 0; q < 4; ++q)
      gl_lds16(src + (size_t)q * rstep, dst + (q << 12) + tid * 16);
  };

  int rb, cb;
  decode(blockIdx.x, rb, cb);
  const unsigned char* paCur = desc8 + (size_t)(rb * TILE) * D + lane_off;
  const unsigned char* pbCur = desc8 + (size_t)(cb * TILE) * D + lane_off;

  f32x4 acc[4][4];
#pragma unroll
  for (int m = 0; m < 4; ++m)
#pragma unroll
    for (int n = 0; n < 4; ++n) acc[m][n] = (f32x4){0.f, 0.f, 0.f, 0.f};

  // prologue: first tile's first K-tile (8 events)
  __builtin_amdgcn_sched_barrier(0);
  stage(paCur, &lA8[0][0][0]);
  stage(pbCur, &lB8[0][0][0]);
  __builtin_amdgcn_sched_barrier(0);

  int gs = 0;  // global K-step counter (bu = gs&1)
  for (int j = blockIdx.x; j < T; j += G) {
    const int row0 = rb * TILE;
    const int col0 = cb * TILE;
    const bool upper = (cb != rb);
    const bool hasNext = (j + G < T);
    int nrb = 0, ncb = 0;
    const unsigned char *paNext = nullptr, *pbNext = nullptr;
    if (hasNext) {
      decode(j + G, nrb, ncb);
      paNext = desc8 + (size_t)(nrb * TILE) * D + lane_off;
      pbNext = desc8 + (size_t)(ncb * TILE) * D + lane_off;
    }

    for (int ts = 0; ts < NT; ++ts) {
      const int bu = gs & 1;
      // prefetch (8 events): next K-tile, or next tile's first K-tile
      if (ts + 1 < NT) {
        stage(paCur + ((ts + 1) << 7), &lA8[bu ^ 1][0][0]);
        stage(pbCur + ((ts + 1) << 7), &lB8[bu ^ 1][0][0]);
        __builtin_amdgcn_sched_barrier(0);
        asm volatile("s_waitcnt vmcnt(8)" ::: "memory");
      } else if (hasNext) {
        stage(paNext, &lA8[bu ^ 1][0][0]);
        stage(pbNext, &lB8[bu ^ 1][0][0]);
        __builtin_amdgcn_sched_barrier(0);
        asm volatile("s_waitcnt vmcnt(8)" ::: "memory");
      } else {
        asm volatile("s_waitcnt vmcnt(0)" ::: "memory");
      }
      __builtin_amdgcn_sched_barrier(0);
      __builtin_amdgcn_s_barrier();  // buf[bu] globally ready
      __builtin_amdgcn_sched_barrier(0);

      // 16 ds_read_b128 (128B rows, row&7 XOR — zero conflicts, R17)
      llong2 av[4][2], bv[4][2];
#pragma unroll
      for (int m = 0; m < 4; ++m) {
        const int row = wrow + (m << 4) + lr;
#pragma unroll
        for (int j2 = 0; j2 < 2; ++j2) {
          const int ch = ((j2 << 2) + kg) ^ (row & 7);
          av[m][j2] =
              *reinterpret_cast<const llong2*>(&lA8[bu][row][ch << 4]);
        }
      }
#pragma unroll
      for (int n = 0; n < 4; ++n) {
        const int row = wcol + (n << 4) + lr;
#pragma unroll
        for (int j2 = 0; j2 < 2; ++j2) {
          const int ch = ((j2 << 2) + kg) ^ (row & 7);
          bv[n][j2] =
              *reinterpret_cast<const llong2*>(&lB8[bu][row][ch << 4]);
        }
      }
      __builtin_amdgcn_sched_barrier(0);
      asm volatile("s_waitcnt lgkmcnt(0)" ::: "memory");
      __builtin_amdgcn_sched_barrier(0);  // rule #18
      __builtin_amdgcn_s_setprio(1);
#pragma unroll
      for (int j2 = 0; j2 < 2; ++j2)
#pragma unroll
        for (int kk = 0; kk < 2; ++kk)
#pragma unroll
          for (int m = 0; m < 4; ++m)
#pragma unroll
            for (int n = 0; n < 4; ++n)
              acc[m][n] = __builtin_amdgcn_mfma_f32_16x16x32_fp8_fp8(
                  av[m][j2][kk], bv[n][j2][kk], acc[m][n], 0, 0, 0);
      __builtin_amdgcn_s_setprio(0);
      __builtin_amdgcn_sched_barrier(0);
      __builtin_amdgcn_s_barrier();  // all waves done reading buf[bu]
      ++gs;
    }

    // ---- epilogue (meta direct from global; raw barriers keep the
    //      cross-tile prefetch in flight) ----
    int cseq[4], ctim[4], gcol[4];
#pragma unroll
    for (int n = 0; n < 4; ++n) {
      const int cl = wcol + (n << 4) + lr;
      gcol[n] = col0 + cl;
      cseq[n] = seq[gcol[n]];
      ctim[n] = tmid[gcol[n]];
    }
    float colse[4] = {0.f, 0.f, 0.f, 0.f};
    float colpd[4] = {0.f, 0.f, 0.f, 0.f};
    float colpc[4] = {0.f, 0.f, 0.f, 0.f};

#pragma unroll
    for (int m = 0; m < 4; ++m) {
#pragma unroll
      for (int reg = 0; reg < 4; ++reg) {
        const int rl = wrow + (m << 4) + (kg << 2) + reg;
        const int growg = row0 + rl;
        const int rs = seq[growg];
        const int rt = tmid[growg];
        float se = 0.f, pd = 0.f, pcnt = 0.f;
#pragma unroll
        for (int n = 0; n < 4; ++n) {
          const float dot = acc[m][n][reg];
          const float e = exp2f(fmaf(dot, K2C8, -K2C));
          const bool nd = (growg != gcol[n]);
          int dt = rt - ctim[n];
          dt = dt < 0 ? -dt : dt;
          const bool pos = nd && (rs == cseq[n]) && (dt < TIME_THR);
          const float ev = nd ? e : 0.f;
          const float dv = pos ? dot : 0.f;
          const float cv = pos ? 1.f : 0.f;
          se += ev;
          pd += dv;
          pcnt += cv;
          colse[n] += ev;
          colpd[n] += dv;
          colpc[n] += cv;
        }
#pragma unroll
        for (int s = 1; s < 16; s <<= 1) {
          se += __shfl_xor(se, s);
          pd += __shfl_xor(pd, s);
          pcnt += __shfl_xor(pcnt, s);
        }
        if (lr == 0) {
          const int half = wcol >> 6;
          float* rr3 = redR + ((size_t)(half * TILE + rl)) * 3;
          rr3[0] = se;
          rr3[1] = pd;
          rr3[2] = pcnt;
        }
      }
    }
    if (upper) {
#pragma unroll
      for (int n = 0; n < 4; ++n) {
        float cs = colse[n], cp = colpd[n], cc = colpc[n];
        cs += __shfl_xor(cs, 16);
        cp += __shfl_xor(cp, 16);
        cc += __shfl_xor(cc, 16);
        cs += __shfl_xor(cs, 32);
        cp += __shfl_xor(cp, 32);
        cc += __shfl_xor(cc, 32);
        if (l < 16) {
          const int half = wrow >> 6;
          const int cl = wcol + (n << 4) + lr;
          float* cr3 = redC + ((size_t)(half * TILE + cl)) * 3;
          cr3[0] = cs;
          cr3[1] = cp;
          cr3[2] = cc;
        }
      }
    }
    // red buffers visible (LDS only — do NOT drain vmcnt)
    asm volatile("s_waitcnt lgkmcnt(0)" ::: "memory");
    __builtin_amdgcn_sched_barrier(0);
    __builtin_amdgcn_s_barrier();
    __builtin_amdgcn_sched_barrier(0);

    if (tid < TILE) {
      const int row = tid;
      const float se =
          redR[(size_t)row * 3 + 0] + redR[(size_t)(TILE + row) * 3 + 0];
      const float pd =
          redR[(size_t)row * 3 + 1] + redR[(size_t)(TILE + row) * 3 + 1];
      const float pc =
          redR[(size_t)row * 3 + 2] + redR[(size_t)(TILE + row) * 3 + 2];
      const size_t o = (size_t)cb * B + row0 + row;
      p_se[o] = se;
      p_ps[o] = pd * INV_T64;
      p_pc[o] = pc;
    } else if (upper) {
      const int col = tid - TILE;
      const float se =
          redC[(size_t)col * 3 + 0] + redC[(size_t)(TILE + col) * 3 + 0];
      const float pd =
          redC[(size_t)col * 3 + 1] + redC[(size_t)(TILE + col) * 3 + 1];
      const float pc =
          redC[(size_t)col * 3 + 2] + redC[(size_t)(TILE + col) * 3 + 2];
      const size_t o = (size_t)rb * B + col0 + col;
      p_se[o] = se;
      p_ps[o] = pd * INV_T64;
      p_pc[o] = pc;
    }
    // redR/redC reads above are protected from next tile's epilogue writes
    // by the (>=2) K-loop barriers of the next tile.

    // advance to next tile; reset accumulator
    rb = nrb;
    cb = ncb;
    paCur = paNext;
    pbCur = pbNext;
#pragma unroll
    for (int m = 0; m < 4; ++m)
#pragma unroll
      for (int n = 0; n < 4; ++n) acc[m][n] = (f32x4){0.f, 0.f, 0.f, 0.f};
  }
}

// ===================== fp32 fallback (non-persistent, atomic) ===============
__global__ __launch_bounds__(256, 2) void infonce_fb(
    const float* __restrict__ desc, const int* __restrict__ seq,
    const int* __restrict__ tmid, float* __restrict__ a_se,
    float* __restrict__ a_ps, float* __restrict__ a_pc, int B, int D, int NB) {
  __shared__ __align__(16) unsigned short lAw[TILE][64];
  __shared__ __align__(16) unsigned short lBw[TILE][64];
  __shared__ int mseq_r[TILE], mtim_r[TILE], mseq_c[TILE], mtim_c[TILE];
  typedef __attribute__((ext_vector_type(8))) short short8v;

  const int T = NB * (NB + 1) / 2;
  int t = blockIdx.x;
  if ((T & 7) == 0) t = (t & 7) * (T >> 3) + (t >> 3);
  float fn = (float)NB + 0.5f;
  int r = (int)(fn - sqrtf(fmaxf(fn * fn - 2.0f * (float)t, 0.0f)));
  if (r < 0) r = 0;
  if (r > NB - 1) r = NB - 1;
  auto Sf = [NB](int rr) { return rr * NB - ((rr * (rr - 1)) >> 1); };
  while (r > 0 && Sf(r) > t) --r;
  while (r < NB - 1 && Sf(r + 1) <= t) ++r;
  const int rb = r;
  const int cb = rb + (t - Sf(rb));
  const bool upper = (cb != rb);
  const int row0 = rb * TILE;
  const int col0 = cb * TILE;

  const int tid = threadIdx.x;
  const int l = tid & 63;
  const int w = tid >> 6;
  const int wrow = (w >> 1) << 6;
  const int wcol = (w & 1) << 6;
  const int lr = l & 15;
  const int kg = l >> 4;
  const int sr = tid >> 3;
  const int sc = tid & 7;

  if (tid < TILE) {
    mseq_r[tid] = seq[row0 + tid];
    mtim_r[tid] = tmid[row0 + tid];
    mseq_c[tid] = seq[col0 + tid];
    mtim_c[tid] = tmid[col0 + tid];
  }

  f32x4 acc[4][4];
#pragma unroll
  for (int m = 0; m < 4; ++m)
#pragma unroll
    for (int n = 0; n < 4; ++n) acc[m][n] = (f32x4){0.f, 0.f, 0.f, 0.f};

  for (int k0 = 0; k0 < D; k0 += 64) {
    __syncthreads();
#pragma unroll
    for (int p = 0; p < 4; ++p) {
      const int rr = (p << 5) + sr;
      const float* gA = desc + (size_t)(row0 + rr) * D + k0 + (sc << 3);
      const float4 fa0 = *reinterpret_cast<const float4*>(gA);
      const float4 fa1 = *reinterpret_cast<const float4*>(gA + 4);
      const float* gB = desc + (size_t)(col0 + rr) * D + k0 + (sc << 3);
      const float4 fb0 = *reinterpret_cast<const float4*>(gB);
      const float4 fb1 = *reinterpret_cast<const float4*>(gB + 4);
      uint4 wa, wb;
      wa.x = pack_bf16x2(fa0.x, fa0.y);
      wa.y = pack_bf16x2(fa0.z, fa0.w);
      wa.z = pack_bf16x2(fa1.x, fa1.y);
      wa.w = pack_bf16x2(fa1.z, fa1.w);
      wb.x = pack_bf16x2(fb0.x, fb0.y);
      wb.y = pack_bf16x2(fb0.z, fb0.w);
      wb.z = pack_bf16x2(fb1.x, fb1.y);
      wb.w = pack_bf16x2(fb1.z, fb1.w);
      const int dst = (sc ^ (rr & 7)) << 3;
      *reinterpret_cast<uint4*>(&lAw[rr][dst]) = wa;
      *reinterpret_cast<uint4*>(&lBw[rr][dst]) = wb;
    }
    __syncthreads();
#pragma unroll
    for (int kk = 0; kk < 2; ++kk) {
      short8v af[4], bf[4];
#pragma unroll
      for (int m = 0; m < 4; ++m) {
        const int rowa = wrow + (m << 4) + lr;
        const int ch = ((kk << 2) + kg) ^ (rowa & 7);
        af[m] = *reinterpret_cast<const short8v*>(&lAw[rowa][ch << 3]);
      }
#pragma unroll
      for (int n = 0; n < 4; ++n) {
        const int rowb = wcol + (n << 4) + lr;
        const int ch = ((kk << 2) + kg) ^ (rowb & 7);
        bf[n] = *reinterpret_cast<const short8v*>(&lBw[rowb][ch << 3]);
      }
#pragma unroll
      for (int m = 0; m < 4; ++m)
#pragma unroll
        for (int n = 0; n < 4; ++n)
          acc[m][n] = __builtin_amdgcn_mfma_f32_16x16x32_bf16(af[m], bf[n],
                                                              acc[m][n], 0, 0, 0);
    }
  }
  __syncthreads();

  int cseq[4], ctim[4], gcol[4];
#pragma unroll
  for (int n = 0; n < 4; ++n) {
    const int cl = wcol + (n << 4) + lr;
    cseq[n] = mseq_c[cl];
    ctim[n] = mtim_c[cl];
    gcol[n] = col0 + cl;
  }
  float colse[4] = {0.f, 0.f, 0.f, 0.f};
  float colpd[4] = {0.f, 0.f, 0.f, 0.f};
  float colpc[4] = {0.f, 0.f, 0.f, 0.f};

#pragma unroll
  for (int m = 0; m < 4; ++m) {
#pragma unroll
    for (int reg = 0; reg < 4; ++reg) {
      const int rl = wrow + (m << 4) + (kg << 2) + reg;
      const int growg = row0 + rl;
      const int rs = mseq_r[rl];
      const int rt = mtim_r[rl];
      float se = 0.f, pd = 0.f, pcnt = 0.f;
#pragma unroll
      for (int n = 0; n < 4; ++n) {
        const float dot = acc[m][n][reg];
        const float e = exp2f(fmaf(dot, K2C, -K2C));
        const bool nd = (growg != gcol[n]);
        int dt = rt - ctim[n];
        dt = dt < 0 ? -dt : dt;
        const bool pos = nd && (rs == cseq[n]) && (dt < TIME_THR);
        const float ev = nd ? e : 0.f;
        const float dv = pos ? dot : 0.f;
        const float cv = pos ? 1.f : 0.f;
        se += ev;
        pd += dv;
        pcnt += cv;
        if (upper) {
          colse[n] += ev;
          colpd[n] += dv;
          colpc[n] += cv;
        }
      }
#pragma unroll
      for (int s = 1; s < 16; s <<= 1) {
        se += __shfl_xor(se, s);
        pd += __shfl_xor(pd, s);
        pcnt += __shfl_xor(pcnt, s);
      }
      if ((l & 15) == 0) {
        atomicAdd(&a_se[growg], se);
        atomicAdd(&a_ps[growg], pd * INV_T);
        atomicAdd(&a_pc[growg], pcnt);
      }
    }
  }
  if (upper) {
#pragma unroll
    for (int n = 0; n < 4; ++n) {
      float cs = colse[n], cp = colpd[n], cc = colpc[n];
      cs += __shfl_xor(cs, 16);
      cp += __shfl_xor(cp, 16);
      cc += __shfl_xor(cc, 16);
      cs += __shfl_xor(cs, 32);
      cp += __shfl_xor(cp, 32);
      cc += __shfl_xor(cc, 32);
      if (kg == 0) {
        atomicAdd(&a_se[gcol[n]], cs);
        atomicAdd(&a_ps[gcol[n]], cp * INV_T);
        atomicAdd(&a_pc[gcol[n]], cc);
      }
    }
  }
}

// fp32 -> fp8 e4m3 (x8 scale), K-tile-128 interleave + row&7 XOR.
__global__ __launch_bounds__(256) void conv_fp8(const float* __restrict__ in,
                                                unsigned char* __restrict__ out,
                                                int D, int nchunk) {
  const int u = blockIdx.x * 256 + threadIdx.x;
  if (u >= nchunk) return;
  const int cpr = D >> 4;
  const int r = u / cpr;
  const int cc = u - r * cpr;
  const int kt = cc >> 3;
  const int p = cc & 7;
  const int g = p ^ (r & 7);
  const int j2 = g >> 2;
  const int kgc = g & 3;
  const float* src = in + (size_t)r * D + (kt << 7) + (j2 << 6) + (kgc << 3);
  const float4 f0 = *reinterpret_cast<const float4*>(src);
  const float4 f1 = *reinterpret_cast<const float4*>(src + 4);
  const float4 g0 = *reinterpret_cast<const float4*>(src + 32);
  const float4 g1 = *reinterpret_cast<const float4*>(src + 36);
  unsigned char b[16];
  b[0] = f32_to_e4m3(f0.x * 8.f);
  b[1] = f32_to_e4m3(f0.y * 8.f);
  b[2] = f32_to_e4m3(f0.z * 8.f);
  b[3] = f32_to_e4m3(f0.w * 8.f);
  b[4] = f32_to_e4m3(f1.x * 8.f);
  b[5] = f32_to_e4m3(f1.y * 8.f);
  b[6] = f32_to_e4m3(f1.z * 8.f);
  b[7] = f32_to_e4m3(f1.w * 8.f);
  b[8] = f32_to_e4m3(g0.x * 8.f);
  b[9] = f32_to_e4m3(g0.y * 8.f);
  b[10] = f32_to_e4m3(g0.z * 8.f);
  b[11] = f32_to_e4m3(g0.w * 8.f);
  b[12] = f32_to_e4m3(g1.x * 8.f);
  b[13] = f32_to_e4m3(g1.y * 8.f);
  b[14] = f32_to_e4m3(g1.z * 8.f);
  b[15] = f32_to_e4m3(g1.w * 8.f);
  uint4 wv;
  unsigned* wp = (unsigned*)&wv;
#pragma unroll
  for (int d = 0; d < 4; ++d)
    wp[d] = (unsigned)b[d * 4] | ((unsigned)b[d * 4 + 1] << 8) |
            ((unsigned)b[d * 4 + 2] << 16) | ((unsigned)b[d * 4 + 3] << 24);
  *reinterpret_cast<uint4*>(out + (size_t)u * 16) = wv;
}

// 4 threads per row (NB quarters), 64 rows/block -> B/64 blocks.
__global__ __launch_bounds__(256) void reduce_parts4(
    const float* __restrict__ p_se, const float* __restrict__ p_ps,
    const float* __restrict__ p_pc, float* __restrict__ bnum,
    float* __restrict__ bcnt, int B, int NB) {
  const int tid = threadIdx.x;
  const int rloc = tid & 63;
  const int chunk = tid >> 6;
  const int row = blockIdx.x * 64 + rloc;
  const int jpc = NB >> 2;
  float se = 0.f, ps = 0.f, pc = 0.f;
  for (int j = chunk * jpc; j < (chunk + 1) * jpc; ++j) {
    const size_t o = (size_t)j * B + row;
    se += p_se[o];
    ps += p_ps[o];
    pc += p_pc[o];
  }
  __shared__ float s3[3][4][64];
  s3[0][chunk][rloc] = se;
  s3[1][chunk][rloc] = ps;
  s3[2][chunk][rloc] = pc;
  __syncthreads();
  if (tid < 64) {
    const float tse = s3[0][0][tid] + s3[0][1][tid] + s3[0][2][tid] + s3[0][3][tid];
    const float tps = s3[1][0][tid] + s3[1][1][tid] + s3[1][2][tid] + s3[1][3][tid];
    const float tpc = s3[2][0][tid] + s3[2][1][tid] + s3[2][2][tid] + s3[2][3][tid];
    float a = tpc * (logf(tse) + INV_T) - tps;
    float b = tpc;
#pragma unroll
    for (int s = 1; s < 64; s <<= 1) {
      a += __shfl_xor(a, s);
      b += __shfl_xor(b, s);
    }
    if (tid == 0) {
      bnum[blockIdx.x] = a;
      bcnt[blockIdx.x] = b;
    }
  }
}

__global__ __launch_bounds__(256) void final_reduce(
    const float* __restrict__ bnum, const float* __restrict__ bcnt,
    float* __restrict__ out, int n) {
  __shared__ float sn[256];
  __shared__ float sc[256];
  const int tid = threadIdx.x;
  float a = 0.f, b = 0.f;
  for (int i = tid; i < n; i += 256) {
    a += bnum[i];
    b += bcnt[i];
  }
  sn[tid] = a;
  sc[tid] = b;
  __syncthreads();
  for (int s = 128; s > 0; s >>= 1) {
    if (tid < s) {
      sn[tid] += sn[tid + s];
      sc[tid] += sc[tid + s];
    }
    __syncthreads();
  }
  if (tid == 0) out[0] = sn[0] / fmaxf(sc[0], 1.f);
}

__global__ __launch_bounds__(1024) void infonce_finalize(
    const float* __restrict__ a_se, const float* __restrict__ a_ps,
    const float* __restrict__ a_pc, float* __restrict__ out, int B) {
  __shared__ float sn[1024];
  __shared__ float sc[1024];
  const int tid = threadIdx.x;
  float num = 0.f, cnt = 0.f;
  for (int i = tid; i < B; i += 1024) {
    const float c = a_pc[i];
    num += c * (logf(a_se[i]) + INV_T) - a_ps[i];
    cnt += c;
  }
  sn[tid] = num;
  sc[tid] = cnt;
  __syncthreads();
  for (int s = 512; s > 0; s >>= 1) {
    if (tid < s) {
      sn[tid] += sn[tid + s];
      sc[tid] += sc[tid + s];
    }
    __syncthreads();
  }
  if (tid == 0) out[0] = sn[0] / fmaxf(sc[0], 1.f);
}

extern "C" void kernel_launch(void* const* d_in, const int* in_sizes, int n_in,
                              void* d_out, int out_size, void* d_ws, size_t ws_size,
                              hipStream_t stream) {
  (void)n_in;
  (void)out_size;
  const float* desc = (const float*)d_in[0];
  const int* seq = (const int*)d_in[1];
  const int* tmid = (const int*)d_in[2];
  const int B = in_sizes[1];
  const int D = in_sizes[0] / B;
  const int NB = B / TILE;
  const int T = NB * (NB + 1) / 2;

  const size_t desc8_bytes = (size_t)B * D;
  const size_t parts_elems = (size_t)B * NB;
  const size_t nb1 = (size_t)B / 64;
  const size_t need8 = desc8_bytes + 3 * parts_elems * 4 + 2 * nb1 * 4;

  if ((B & 255) == 0 && (D & 127) == 0 && ws_size >= need8) {
    unsigned char* desc8 = (unsigned char*)d_ws;
    float* p_se = (float*)((char*)d_ws + desc8_bytes);
    float* p_ps = p_se + parts_elems;
    float* p_pc = p_ps + parts_elems;
    float* bnum = p_pc + parts_elems;
    float* bcnt = bnum + nb1;
    const int nchunk = (int)(((size_t)B * D) >> 4);
    conv_fp8<<<(nchunk + 255) / 256, 256, 0, stream>>>(desc, desc8, D, nchunk);
    const int G = T < 512 ? T : 512;
    infonce_pers<<<G, 256, 0, stream>>>(desc8, seq, tmid, p_se, p_ps, p_pc, B,
                                        D, NB, G);
    const int nrb = B / 64;
    reduce_parts4<<<nrb, 256, 0, stream>>>(p_se, p_ps, p_pc, bnum, bcnt, B, NB);
    final_reduce<<<1, 256, 0, stream>>>(bnum, bcnt, (float*)d_out, nrb);
  } else {
    float* a_se = (float*)d_ws;
    float* a_ps = a_se + B;
    float* a_pc = a_ps + B;
    hipMemsetAsync(d_ws, 0, (size_t)3 * B * sizeof(float), stream);
    infonce_fb<<<T, 256, 0, stream>>>(desc, seq, tmid, a_se, a_ps, a_pc, B, D,
                                      NB);
    infonce_finalize<<<1, 1024, 0, stream>>>(a_se, a_ps, a_pc, (float*)d_out, B);
  }
}

// Round 20
// 91.664 us; speedup vs baseline: 1.1973x; 1.0111x over previous
//
#include <hip/hip_runtime.h>
#include <math.h>

#define TILE 128

typedef __attribute__((ext_vector_type(4))) float f32x4;
typedef __attribute__((ext_vector_type(2))) long long llong2;

// constants: 1/T, 1/(T*ln2); fp8 path uses x8-scaled inputs -> /64 variants
#define INV_T    14.285714285714286f
#define K2C      20.60992915f
#define K2C8     0.32203014296875f    // K2C / 64
#define INV_T64  0.22321428571428573f // INV_T / 64
#define TIME_THR 5000000

__device__ __forceinline__ unsigned pack_bf16x2(float lo, float hi) {
  unsigned a = __float_as_uint(lo);
  unsigned b = __float_as_uint(hi);
  a = (a + 0x7FFFu + ((a >> 16) & 1u)) >> 16;
  b = (b + 0x7FFFu + ((b >> 16) & 1u)) & 0xFFFF0000u;
  return b | a;
}

// float -> OCP e4m3fn, round-to-nearest-even, clamp to 448.
__device__ __forceinline__ unsigned f32_to_e4m3(float x) {
  unsigned u = __float_as_uint(x);
  unsigned s = (u >> 24) & 0x80u;
  int e = (int)((u >> 23) & 0xffu) - 127;
  unsigned m = u & 0x7fffffu;
  if (e < -9) return s;
  if (e < -6) {
    int sh = 20 + (-6 - e);
    unsigned full = (1u << 23) | m;
    unsigned q = full >> sh;
    unsigned rem = full & ((1u << sh) - 1u);
    unsigned half = 1u << (sh - 1);
    if (rem > half || (rem == half && (q & 1u))) q++;
    return s | q;
  }
  unsigned q = m >> 20;
  unsigned rem = m & 0xfffffu;
  if (rem > 0x80000u || (rem == 0x80000u && (q & 1u))) q++;
  int ee = e;
  if (q == 8u) { q = 0u; ee++; }
  if (ee > 8 || (ee == 8 && q == 7u)) return s | 0x7eu;
  return s | (unsigned)((ee + 7) << 3) | q;
}

__device__ __forceinline__ void gl_lds16(const void* g, void* l) {
  __builtin_amdgcn_global_load_lds(
      (const __attribute__((address_space(1))) unsigned int*)g,
      (__attribute__((address_space(3))) unsigned int*)l, 16, 0, 0);
}

// PERSISTENT fp8 kernel (R19, passing): grid = min(T,512); per-tile cross
// prefetch in the same 8-event FIFO slot; raw-barrier epilogue with
// dedicated red buffers; (256,2), 128B LDS rows, 0 bank conflicts.
__global__ __launch_bounds__(256, 2) void infonce_pers(
    const unsigned char* __restrict__ desc8, const int* __restrict__ seq,
    const int* __restrict__ tmid, float* __restrict__ p_se,
    float* __restrict__ p_ps, float* __restrict__ p_pc, int B, int D, int NB,
    int G) {
  __shared__ __align__(16) unsigned char lA8[2][TILE][128];
  __shared__ __align__(16) unsigned char lB8[2][TILE][128];
  __shared__ float redR[2 * TILE * 3];
  __shared__ float redC[2 * TILE * 3];

  const int T = NB * (NB + 1) / 2;
  const int tid = threadIdx.x;
  const int l = tid & 63;
  const int w = tid >> 6;          // wave id 0..3 (2x2)
  const int wrow = (w >> 1) << 6;  // 0 or 64
  const int wcol = (w & 1) << 6;   // 0 or 64
  const int lr = l & 15;
  const int kg = l >> 4;
  const int NT = D >> 7;  // K-tile = 128

  auto decode = [&](int idx, int& rb_, int& cb_) {
    int t = idx;
    if ((T & 7) == 0) t = (t & 7) * (T >> 3) + (t >> 3);
    float fn = (float)NB + 0.5f;
    int r = (int)(fn - sqrtf(fmaxf(fn * fn - 2.0f * (float)t, 0.0f)));
    if (r < 0) r = 0;
    if (r > NB - 1) r = NB - 1;
    auto Sf = [&](int rr) { return rr * NB - ((rr * (rr - 1)) >> 1); };
    while (r > 0 && Sf(r) > t) --r;
    while (r < NB - 1 && Sf(r + 1) <= t) ++r;
    rb_ = r;
    cb_ = r + (t - Sf(r));
  };

  const size_t rstep = (size_t)32 * D;
  const size_t lane_off = (size_t)(tid >> 3) * D + (size_t)(tid & 7) * 16;
  auto stage = [&](const unsigned char* src, unsigned char* dst) {
#pragma unroll
    for (int q = 0; q < 4; ++q)
      gl_lds16(src + (size_t)q * rstep, dst + (q << 12) + tid * 16);
  };

  int rb, cb;
  decode(blockIdx.x, rb, cb);
  const unsigned char* paCur = desc8 + (size_t)(rb * TILE) * D + lane_off;
  const unsigned char* pbCur = desc8 + (size_t)(cb * TILE) * D + lane_off;

  f32x4 acc[4][4];
#pragma unroll
  for (int m = 0; m < 4; ++m)
#pragma unroll
    for (int n = 0; n < 4; ++n) acc[m][n] = (f32x4){0.f, 0.f, 0.f, 0.f};

  __builtin_amdgcn_sched_barrier(0);
  stage(paCur, &lA8[0][0][0]);
  stage(pbCur, &lB8[0][0][0]);
  __builtin_amdgcn_sched_barrier(0);

  int gs = 0;  // global K-step counter (bu = gs&1)
  for (int j = blockIdx.x; j < T; j += G) {
    const int row0 = rb * TILE;
    const int col0 = cb * TILE;
    const bool upper = (cb != rb);
    const bool hasNext = (j + G < T);
    int nrb = 0, ncb = 0;
    const unsigned char *paNext = nullptr, *pbNext = nullptr;
    if (hasNext) {
      decode(j + G, nrb, ncb);
      paNext = desc8 + (size_t)(nrb * TILE) * D + lane_off;
      pbNext = desc8 + (size_t)(ncb * TILE) * D + lane_off;
    }

    for (int ts = 0; ts < NT; ++ts) {
      const int bu = gs & 1;
      if (ts + 1 < NT) {
        stage(paCur + ((ts + 1) << 7), &lA8[bu ^ 1][0][0]);
        stage(pbCur + ((ts + 1) << 7), &lB8[bu ^ 1][0][0]);
        __builtin_amdgcn_sched_barrier(0);
        asm volatile("s_waitcnt vmcnt(8)" ::: "memory");
      } else if (hasNext) {
        stage(paNext, &lA8[bu ^ 1][0][0]);
        stage(pbNext, &lB8[bu ^ 1][0][0]);
        __builtin_amdgcn_sched_barrier(0);
        asm volatile("s_waitcnt vmcnt(8)" ::: "memory");
      } else {
        asm volatile("s_waitcnt vmcnt(0)" ::: "memory");
      }
      __builtin_amdgcn_sched_barrier(0);
      __builtin_amdgcn_s_barrier();  // buf[bu] globally ready
      __builtin_amdgcn_sched_barrier(0);

      llong2 av[4][2], bv[4][2];
#pragma unroll
      for (int m = 0; m < 4; ++m) {
        const int row = wrow + (m << 4) + lr;
#pragma unroll
        for (int j2 = 0; j2 < 2; ++j2) {
          const int ch = ((j2 << 2) + kg) ^ (row & 7);
          av[m][j2] =
              *reinterpret_cast<const llong2*>(&lA8[bu][row][ch << 4]);
        }
      }
#pragma unroll
      for (int n = 0; n < 4; ++n) {
        const int row = wcol + (n << 4) + lr;
#pragma unroll
        for (int j2 = 0; j2 < 2; ++j2) {
          const int ch = ((j2 << 2) + kg) ^ (row & 7);
          bv[n][j2] =
              *reinterpret_cast<const llong2*>(&lB8[bu][row][ch << 4]);
        }
      }
      __builtin_amdgcn_sched_barrier(0);
      asm volatile("s_waitcnt lgkmcnt(0)" ::: "memory");
      __builtin_amdgcn_sched_barrier(0);  // rule #18
      __builtin_amdgcn_s_setprio(1);
#pragma unroll
      for (int j2 = 0; j2 < 2; ++j2)
#pragma unroll
        for (int kk = 0; kk < 2; ++kk)
#pragma unroll
          for (int m = 0; m < 4; ++m)
#pragma unroll
            for (int n = 0; n < 4; ++n)
              acc[m][n] = __builtin_amdgcn_mfma_f32_16x16x32_fp8_fp8(
                  av[m][j2][kk], bv[n][j2][kk], acc[m][n], 0, 0, 0);
      __builtin_amdgcn_s_setprio(0);
      __builtin_amdgcn_sched_barrier(0);
      __builtin_amdgcn_s_barrier();  // all waves done reading buf[bu]
      ++gs;
    }

    // ---- epilogue (raw barriers keep the cross-tile prefetch alive) ----
    int cseq[4], ctim[4], gcol[4];
#pragma unroll
    for (int n = 0; n < 4; ++n) {
      const int cl = wcol + (n << 4) + lr;
      gcol[n] = col0 + cl;
      cseq[n] = seq[gcol[n]];
      ctim[n] = tmid[gcol[n]];
    }
    float colse[4] = {0.f, 0.f, 0.f, 0.f};
    float colpd[4] = {0.f, 0.f, 0.f, 0.f};
    float colpc[4] = {0.f, 0.f, 0.f, 0.f};

#pragma unroll
    for (int m = 0; m < 4; ++m) {
#pragma unroll
      for (int reg = 0; reg < 4; ++reg) {
        const int rl = wrow + (m << 4) + (kg << 2) + reg;
        const int growg = row0 + rl;
        const int rs = seq[growg];
        const int rt = tmid[growg];
        float se = 0.f, pd = 0.f, pcnt = 0.f;
#pragma unroll
        for (int n = 0; n < 4; ++n) {
          const float dot = acc[m][n][reg];
          const float e = exp2f(fmaf(dot, K2C8, -K2C));
          const bool nd = (growg != gcol[n]);
          int dt = rt - ctim[n];
          dt = dt < 0 ? -dt : dt;
          const bool pos = nd && (rs == cseq[n]) && (dt < TIME_THR);
          const float ev = nd ? e : 0.f;
          const float dv = pos ? dot : 0.f;
          const float cv = pos ? 1.f : 0.f;
          se += ev;
          pd += dv;
          pcnt += cv;
          colse[n] += ev;
          colpd[n] += dv;
          colpc[n] += cv;
        }
#pragma unroll
        for (int s = 1; s < 16; s <<= 1) {
          se += __shfl_xor(se, s);
          pd += __shfl_xor(pd, s);
          pcnt += __shfl_xor(pcnt, s);
        }
        if (lr == 0) {
          const int half = wcol >> 6;
          float* rr3 = redR + ((size_t)(half * TILE + rl)) * 3;
          rr3[0] = se;
          rr3[1] = pd;
          rr3[2] = pcnt;
        }
      }
    }
    if (upper) {
#pragma unroll
      for (int n = 0; n < 4; ++n) {
        float cs = colse[n], cp = colpd[n], cc = colpc[n];
        cs += __shfl_xor(cs, 16);
        cp += __shfl_xor(cp, 16);
        cc += __shfl_xor(cc, 16);
        cs += __shfl_xor(cs, 32);
        cp += __shfl_xor(cp, 32);
        cc += __shfl_xor(cc, 32);
        if (l < 16) {
          const int half = wrow >> 6;
          const int cl = wcol + (n << 4) + lr;
          float* cr3 = redC + ((size_t)(half * TILE + cl)) * 3;
          cr3[0] = cs;
          cr3[1] = cp;
          cr3[2] = cc;
        }
      }
    }
    asm volatile("s_waitcnt lgkmcnt(0)" ::: "memory");
    __builtin_amdgcn_sched_barrier(0);
    __builtin_amdgcn_s_barrier();
    __builtin_amdgcn_sched_barrier(0);

    if (tid < TILE) {
      const int row = tid;
      const float se =
          redR[(size_t)row * 3 + 0] + redR[(size_t)(TILE + row) * 3 + 0];
      const float pd =
          redR[(size_t)row * 3 + 1] + redR[(size_t)(TILE + row) * 3 + 1];
      const float pc =
          redR[(size_t)row * 3 + 2] + redR[(size_t)(TILE + row) * 3 + 2];
      const size_t o = (size_t)cb * B + row0 + row;
      p_se[o] = se;
      p_ps[o] = pd * INV_T64;
      p_pc[o] = pc;
    } else if (upper) {
      const int col = tid - TILE;
      const float se =
          redC[(size_t)col * 3 + 0] + redC[(size_t)(TILE + col) * 3 + 0];
      const float pd =
          redC[(size_t)col * 3 + 1] + redC[(size_t)(TILE + col) * 3 + 1];
      const float pc =
          redC[(size_t)col * 3 + 2] + redC[(size_t)(TILE + col) * 3 + 2];
      const size_t o = (size_t)rb * B + col0 + col;
      p_se[o] = se;
      p_ps[o] = pd * INV_T64;
      p_pc[o] = pc;
    }

    rb = nrb;
    cb = ncb;
    paCur = paNext;
    pbCur = pbNext;
#pragma unroll
    for (int m = 0; m < 4; ++m)
#pragma unroll
      for (int n = 0; n < 4; ++n) acc[m][n] = (f32x4){0.f, 0.f, 0.f, 0.f};
  }
}

// ===================== fp32 fallback (non-persistent, atomic) ===============
__global__ __launch_bounds__(256, 2) void infonce_fb(
    const float* __restrict__ desc, const int* __restrict__ seq,
    const int* __restrict__ tmid, float* __restrict__ a_se,
    float* __restrict__ a_ps, float* __restrict__ a_pc, int B, int D, int NB) {
  __shared__ __align__(16) unsigned short lAw[TILE][64];
  __shared__ __align__(16) unsigned short lBw[TILE][64];
  __shared__ int mseq_r[TILE], mtim_r[TILE], mseq_c[TILE], mtim_c[TILE];
  typedef __attribute__((ext_vector_type(8))) short short8v;

  const int T = NB * (NB + 1) / 2;
  int t = blockIdx.x;
  if ((T & 7) == 0) t = (t & 7) * (T >> 3) + (t >> 3);
  float fn = (float)NB + 0.5f;
  int r = (int)(fn - sqrtf(fmaxf(fn * fn - 2.0f * (float)t, 0.0f)));
  if (r < 0) r = 0;
  if (r > NB - 1) r = NB - 1;
  auto Sf = [NB](int rr) { return rr * NB - ((rr * (rr - 1)) >> 1); };
  while (r > 0 && Sf(r) > t) --r;
  while (r < NB - 1 && Sf(r + 1) <= t) ++r;
  const int rb = r;
  const int cb = rb + (t - Sf(rb));
  const bool upper = (cb != rb);
  const int row0 = rb * TILE;
  const int col0 = cb * TILE;

  const int tid = threadIdx.x;
  const int l = tid & 63;
  const int w = tid >> 6;
  const int wrow = (w >> 1) << 6;
  const int wcol = (w & 1) << 6;
  const int lr = l & 15;
  const int kg = l >> 4;
  const int sr = tid >> 3;
  const int sc = tid & 7;

  if (tid < TILE) {
    mseq_r[tid] = seq[row0 + tid];
    mtim_r[tid] = tmid[row0 + tid];
    mseq_c[tid] = seq[col0 + tid];
    mtim_c[tid] = tmid[col0 + tid];
  }

  f32x4 acc[4][4];
#pragma unroll
  for (int m = 0; m < 4; ++m)
#pragma unroll
    for (int n = 0; n < 4; ++n) acc[m][n] = (f32x4){0.f, 0.f, 0.f, 0.f};

  for (int k0 = 0; k0 < D; k0 += 64) {
    __syncthreads();
#pragma unroll
    for (int p = 0; p < 4; ++p) {
      const int rr = (p << 5) + sr;
      const float* gA = desc + (size_t)(row0 + rr) * D + k0 + (sc << 3);
      const float4 fa0 = *reinterpret_cast<const float4*>(gA);
      const float4 fa1 = *reinterpret_cast<const float4*>(gA + 4);
      const float* gB = desc + (size_t)(col0 + rr) * D + k0 + (sc << 3);
      const float4 fb0 = *reinterpret_cast<const float4*>(gB);
      const float4 fb1 = *reinterpret_cast<const float4*>(gB + 4);
      uint4 wa, wb;
      wa.x = pack_bf16x2(fa0.x, fa0.y);
      wa.y = pack_bf16x2(fa0.z, fa0.w);
      wa.z = pack_bf16x2(fa1.x, fa1.y);
      wa.w = pack_bf16x2(fa1.z, fa1.w);
      wb.x = pack_bf16x2(fb0.x, fb0.y);
      wb.y = pack_bf16x2(fb0.z, fb0.w);
      wb.z = pack_bf16x2(fb1.x, fb1.y);
      wb.w = pack_bf16x2(fb1.z, fb1.w);
      const int dst = (sc ^ (rr & 7)) << 3;
      *reinterpret_cast<uint4*>(&lAw[rr][dst]) = wa;
      *reinterpret_cast<uint4*>(&lBw[rr][dst]) = wb;
    }
    __syncthreads();
#pragma unroll
    for (int kk = 0; kk < 2; ++kk) {
      short8v af[4], bf[4];
#pragma unroll
      for (int m = 0; m < 4; ++m) {
        const int rowa = wrow + (m << 4) + lr;
        const int ch = ((kk << 2) + kg) ^ (rowa & 7);
        af[m] = *reinterpret_cast<const short8v*>(&lAw[rowa][ch << 3]);
      }
#pragma unroll
      for (int n = 0; n < 4; ++n) {
        const int rowb = wcol + (n << 4) + lr;
        const int ch = ((kk << 2) + kg) ^ (rowb & 7);
        bf[n] = *reinterpret_cast<const short8v*>(&lBw[rowb][ch << 3]);
      }
#pragma unroll
      for (int m = 0; m < 4; ++m)
#pragma unroll
        for (int n = 0; n < 4; ++n)
          acc[m][n] = __builtin_amdgcn_mfma_f32_16x16x32_bf16(af[m], bf[n],
                                                              acc[m][n], 0, 0, 0);
    }
  }
  __syncthreads();

  int cseq[4], ctim[4], gcol[4];
#pragma unroll
  for (int n = 0; n < 4; ++n) {
    const int cl = wcol + (n << 4) + lr;
    cseq[n] = mseq_c[cl];
    ctim[n] = mtim_c[cl];
    gcol[n] = col0 + cl;
  }
  float colse[4] = {0.f, 0.f, 0.f, 0.f};
  float colpd[4] = {0.f, 0.f, 0.f, 0.f};
  float colpc[4] = {0.f, 0.f, 0.f, 0.f};

#pragma unroll
  for (int m = 0; m < 4; ++m) {
#pragma unroll
    for (int reg = 0; reg < 4; ++reg) {
      const int rl = wrow + (m << 4) + (kg << 2) + reg;
      const int growg = row0 + rl;
      const int rs = mseq_r[rl];
      const int rt = mtim_r[rl];
      float se = 0.f, pd = 0.f, pcnt = 0.f;
#pragma unroll
      for (int n = 0; n < 4; ++n) {
        const float dot = acc[m][n][reg];
        const float e = exp2f(fmaf(dot, K2C, -K2C));
        const bool nd = (growg != gcol[n]);
        int dt = rt - ctim[n];
        dt = dt < 0 ? -dt : dt;
        const bool pos = nd && (rs == cseq[n]) && (dt < TIME_THR);
        const float ev = nd ? e : 0.f;
        const float dv = pos ? dot : 0.f;
        const float cv = pos ? 1.f : 0.f;
        se += ev;
        pd += dv;
        pcnt += cv;
        if (upper) {
          colse[n] += ev;
          colpd[n] += dv;
          colpc[n] += cv;
        }
      }
#pragma unroll
      for (int s = 1; s < 16; s <<= 1) {
        se += __shfl_xor(se, s);
        pd += __shfl_xor(pd, s);
        pcnt += __shfl_xor(pcnt, s);
      }
      if ((l & 15) == 0) {
        atomicAdd(&a_se[growg], se);
        atomicAdd(&a_ps[growg], pd * INV_T);
        atomicAdd(&a_pc[growg], pcnt);
      }
    }
  }
  if (upper) {
#pragma unroll
    for (int n = 0; n < 4; ++n) {
      float cs = colse[n], cp = colpd[n], cc = colpc[n];
      cs += __shfl_xor(cs, 16);
      cp += __shfl_xor(cp, 16);
      cc += __shfl_xor(cc, 16);
      cs += __shfl_xor(cs, 32);
      cp += __shfl_xor(cp, 32);
      cc += __shfl_xor(cc, 32);
      if (kg == 0) {
        atomicAdd(&a_se[gcol[n]], cs);
        atomicAdd(&a_ps[gcol[n]], cp * INV_T);
        atomicAdd(&a_pc[gcol[n]], cc);
      }
    }
  }
}

// fp32 -> fp8 e4m3 (x8 scale), COALESCED READ / permuted 8B write.
// Thread v handles 8 consecutive floats at k = (v % (D/8))*8, row
// r = v / (D/8). Output position (inverse of the R17/R19 layout):
// kt = k>>7, j2 = (k>>6)&1, w64 = k&63, half = w64>=32,
// kgc = (w64&31)>>3, p = (4*j2+kgc) ^ (r&7);
// byte addr = r*D + kt*128 + p*16 + half*8.  (Layout byte-identical to
// R19's gather version; wave = one row -> 2KB contiguous reads, stores
// confined to the row's 512B output window.)
__global__ __launch_bounds__(256) void conv_fp8(const float* __restrict__ in,
                                                unsigned char* __restrict__ out,
                                                int D, int ngroups) {
  const int v = blockIdx.x * 256 + threadIdx.x;
  if (v >= ngroups) return;
  const int gpr = D >> 3;  // groups per row
  const int r = v / gpr;
  const int k = (v - r * gpr) << 3;
  const float* src = in + (size_t)r * D + k;
  const float4 f0 = *reinterpret_cast<const float4*>(src);
  const float4 f1 = *reinterpret_cast<const float4*>(src + 4);
  unsigned char b[8];
  b[0] = f32_to_e4m3(f0.x * 8.f);
  b[1] = f32_to_e4m3(f0.y * 8.f);
  b[2] = f32_to_e4m3(f0.z * 8.f);
  b[3] = f32_to_e4m3(f0.w * 8.f);
  b[4] = f32_to_e4m3(f1.x * 8.f);
  b[5] = f32_to_e4m3(f1.y * 8.f);
  b[6] = f32_to_e4m3(f1.z * 8.f);
  b[7] = f32_to_e4m3(f1.w * 8.f);
  const int kt = k >> 7;
  const int j2 = (k >> 6) & 1;
  const int w64 = k & 63;
  const int half = (w64 >= 32) ? 1 : 0;
  const int kgc = (w64 & 31) >> 3;
  const int p = ((j2 << 2) | kgc) ^ (r & 7);
  unsigned long long pk = 0;
#pragma unroll
  for (int d = 0; d < 8; ++d) pk |= ((unsigned long long)b[d]) << (d * 8);
  *reinterpret_cast<unsigned long long*>(
      out + (size_t)r * D + (kt << 7) + (p << 4) + half * 8) = pk;
}

// 4 threads per row (NB quarters), 64 rows/block -> B/64 blocks.
__global__ __launch_bounds__(256) void reduce_parts4(
    const float* __restrict__ p_se, const float* __restrict__ p_ps,
    const float* __restrict__ p_pc, float* __restrict__ bnum,
    float* __restrict__ bcnt, int B, int NB) {
  const int tid = threadIdx.x;
  const int rloc = tid & 63;
  const int chunk = tid >> 6;
  const int row = blockIdx.x * 64 + rloc;
  const int jpc = NB >> 2;
  float se = 0.f, ps = 0.f, pc = 0.f;
  for (int j = chunk * jpc; j < (chunk + 1) * jpc; ++j) {
    const size_t o = (size_t)j * B + row;
    se += p_se[o];
    ps += p_ps[o];
    pc += p_pc[o];
  }
  __shared__ float s3[3][4][64];
  s3[0][chunk][rloc] = se;
  s3[1][chunk][rloc] = ps;
  s3[2][chunk][rloc] = pc;
  __syncthreads();
  if (tid < 64) {
    const float tse = s3[0][0][tid] + s3[0][1][tid] + s3[0][2][tid] + s3[0][3][tid];
    const float tps = s3[1][0][tid] + s3[1][1][tid] + s3[1][2][tid] + s3[1][3][tid];
    const float tpc = s3[2][0][tid] + s3[2][1][tid] + s3[2][2][tid] + s3[2][3][tid];
    float a = tpc * (logf(tse) + INV_T) - tps;
    float b = tpc;
#pragma unroll
    for (int s = 1; s < 64; s <<= 1) {
      a += __shfl_xor(a, s);
      b += __shfl_xor(b, s);
    }
    if (tid == 0) {
      bnum[blockIdx.x] = a;
      bcnt[blockIdx.x] = b;
    }
  }
}

__global__ __launch_bounds__(256) void final_reduce(
    const float* __restrict__ bnum, const float* __restrict__ bcnt,
    float* __restrict__ out, int n) {
  __shared__ float sn[256];
  __shared__ float sc[256];
  const int tid = threadIdx.x;
  float a = 0.f, b = 0.f;
  for (int i = tid; i < n; i += 256) {
    a += bnum[i];
    b += bcnt[i];
  }
  sn[tid] = a;
  sc[tid] = b;
  __syncthreads();
  for (int s = 128; s > 0; s >>= 1) {
    if (tid < s) {
      sn[tid] += sn[tid + s];
      sc[tid] += sc[tid + s];
    }
    __syncthreads();
  }
  if (tid == 0) out[0] = sn[0] / fmaxf(sc[0], 1.f);
}

__global__ __launch_bounds__(1024) void infonce_finalize(
    const float* __restrict__ a_se, const float* __restrict__ a_ps,
    const float* __restrict__ a_pc, float* __restrict__ out, int B) {
  __shared__ float sn[1024];
  __shared__ float sc[1024];
  const int tid = threadIdx.x;
  float num = 0.f, cnt = 0.f;
  for (int i = tid; i < B; i += 1024) {
    const float c = a_pc[i];
    num += c * (logf(a_se[i]) + INV_T) - a_ps[i];
    cnt += c;
  }
  sn[tid] = num;
  sc[tid] = cnt;
  __syncthreads();
  for (int s = 512; s > 0; s >>= 1) {
    if (tid < s) {
      sn[tid] += sn[tid + s];
      sc[tid] += sc[tid + s];
    }
    __syncthreads();
  }
  if (tid == 0) out[0] = sn[0] / fmaxf(sc[0], 1.f);
}

extern "C" void kernel_launch(void* const* d_in, const int* in_sizes, int n_in,
                              void* d_out, int out_size, void* d_ws, size_t ws_size,
                              hipStream_t stream) {
  (void)n_in;
  (void)out_size;
  const float* desc = (const float*)d_in[0];
  const int* seq = (const int*)d_in[1];
  const int* tmid = (const int*)d_in[2];
  const int B = in_sizes[1];
  const int D = in_sizes[0] / B;
  const int NB = B / TILE;
  const int T = NB * (NB + 1) / 2;

  const size_t desc8_bytes = (size_t)B * D;
  const size_t parts_elems = (size_t)B * NB;
  const size_t nb1 = (size_t)B / 64;
  const size_t need8 = desc8_bytes + 3 * parts_elems * 4 + 2 * nb1 * 4;

  if ((B & 255) == 0 && (D & 127) == 0 && ws_size >= need8) {
    unsigned char* desc8 = (unsigned char*)d_ws;
    float* p_se = (float*)((char*)d_ws + desc8_bytes);
    float* p_ps = p_se + parts_elems;
    float* p_pc = p_ps + parts_elems;
    float* bnum = p_pc + parts_elems;
    float* bcnt = bnum + nb1;
    const int ngroups = (int)(((size_t)B * D) >> 3);
    conv_fp8<<<(ngroups + 255) / 256, 256, 0, stream>>>(desc, desc8, D, ngroups);
    const int G = T < 512 ? T : 512;
    infonce_pers<<<G, 256, 0, stream>>>(desc8, seq, tmid, p_se, p_ps, p_pc, B,
                                        D, NB, G);
    const int nrb = B / 64;
    reduce_parts4<<<nrb, 256, 0, stream>>>(p_se, p_ps, p_pc, bnum, bcnt, B, NB);
    final_reduce<<<1, 256, 0, stream>>>(bnum, bcnt, (float*)d_out, nrb);
  } else {
    float* a_se = (float*)d_ws;
    float* a_ps = a_se + B;
    float* a_pc = a_ps + B;
    hipMemsetAsync(d_ws, 0, (size_t)3 * B * sizeof(float), stream);
    infonce_fb<<<T, 256, 0, stream>>>(desc, seq, tmid, a_se, a_ps, a_pc, B, D,
                                      NB);
    infonce_finalize<<<1, 1024, 0, stream>>>(a_se, a_ps, a_pc, (float*)d_out, B);
  }
}